// Round 11
// baseline (70.903 us; speedup 1.0000x reference)
//
#include <hip/hip_runtime.h>
#include <math.h>

// ---------------- problem constants ----------------
#define NROWS 4096
#define DIM   512
#define UNIT  128                  // tile edge
#define NP    (NROWS / UNIT)       // 32 row/col blocks
#define NTILES (NP * (NP + 1) / 2) // 528 lower-triangle tiles (= 8 * 66)
#define KSTEPS (DIM / 32)          // 16 K-steps of 32
#define NSLOT NP                   // 32 partial slots per row (direct+mirror, disjoint)

typedef __bf16 bf16x8 __attribute__((ext_vector_type(8)));
typedef float  f32x4  __attribute__((ext_vector_type(4)));

#define GL16(G, L) __builtin_amdgcn_global_load_lds( \
    (const __attribute__((address_space(1))) void*)(G), \
    (__attribute__((address_space(3))) void*)(L), 16, 0, 0)

// ---------------- kernel 1: row-normalize to bf16 (4 rows/block) ----------------
__global__ __launch_bounds__(256)
void normalize_kernel(const float* __restrict__ X, const float* __restrict__ Y,
                      __bf16* __restrict__ Xn, __bf16* __restrict__ Yn)
{
    const int wid  = threadIdx.x >> 6;
    const int lane = threadIdx.x & 63;
    const int row  = blockIdx.x * 4 + wid;
    const float* src = blockIdx.y ? Y : X;
    __bf16*      dst = blockIdx.y ? Yn : Xn;

    const float4* s4 = reinterpret_cast<const float4*>(src + (size_t)row * DIM);
    float4 v0 = s4[lane * 2 + 0];
    float4 v1 = s4[lane * 2 + 1];
    float ss = v0.x*v0.x + v0.y*v0.y + v0.z*v0.z + v0.w*v0.w
             + v1.x*v1.x + v1.y*v1.y + v1.z*v1.z + v1.w*v1.w;
    #pragma unroll
    for (int m = 1; m < 64; m <<= 1) ss += __shfl_xor(ss, m);
    const float scale = 1.0f / fmaxf(sqrtf(ss), 1e-8f);

    bf16x8 o;
    o[0] = (__bf16)(v0.x * scale); o[1] = (__bf16)(v0.y * scale);
    o[2] = (__bf16)(v0.z * scale); o[3] = (__bf16)(v0.w * scale);
    o[4] = (__bf16)(v1.x * scale); o[5] = (__bf16)(v1.y * scale);
    o[6] = (__bf16)(v1.z * scale); o[7] = (__bf16)(v1.w * scale);
    *reinterpret_cast<bf16x8*>(dst + (size_t)row * DIM + lane * 8) = o;
}

// ---------------- kernel 2: symmetric-triangle gram + exp-sum partials ----------------
// Tile (p, q), q <= p, 128x128 (i-rows = p-block, j-rows = q-block), both matrices.
// 4 waves: m = wid>>1 (0=X/target, 1=Y/pred); iq = wid&1 (i-half of 64).
// Wave computes C[j,i] = sum_k J[j,k]*I[i,k] over 128j x 64i (swapped operands:
// j = fj*16 + (lane>>4)*4 + r lane-local; i = iq*64 + fi*16 + (lane&15)).
// Symmetry: direct row-i sums over j (slot q) + mirror row-j sums over i (slot p,
// only when p != q). Slots are gap-free per row: direct [0..p(r)], mirror [p(r)+1..31].
// Logits a=-simT, b=-simP in [-1,1] -> plain sums S,U,V,Q (no max tracking).
// 64KB LDS -> 2 independent blocks/CU (TLP across block barriers).
// Epilogue is CHUNKED (per fj) to keep live registers small (R6 spilled here).
__global__ __launch_bounds__(256, 2)
void gram_kl_kernel(const __bf16* __restrict__ Xn, const __bf16* __restrict__ Yn,
                    float4* __restrict__ partials)
{
    // 2 stages x 32KB: per stage [JX 8K | JY 8K | IX 8K | IY 8K]
    __shared__ char lds[65536];

    const int tid  = threadIdx.x;
    const int wid  = tid >> 6;     // 0..3
    const int lane = tid & 63;
    const int m  = wid >> 1;       // matrix select
    const int iq = wid & 1;        // i-half

    // XCD-chunked map over 528 = 8 * 66, then triangular decode (q <= p)
    const int glin = (blockIdx.x & 7) * (NTILES / 8) + (blockIdx.x >> 3);
    int p = (int)((sqrtf((float)(8 * glin + 1)) - 1.0f) * 0.5f);
    while ((p + 1) * (p + 2) / 2 <= glin) ++p;
    while (p * (p + 1) / 2 > glin) --p;
    const int q = glin - p * (p + 1) / 2;
    const int i0 = p * UNIT;
    const int j0 = q * UNIT;

    // ---- staging source offsets (pre-swizzled global, linear LDS dest) ----
    // 16B unit u of a panel: row = u>>2, LDS slot u&3 holds global seg (u&3)^((row>>1)&3)
    const int xnib = (((tid & 3) ^ ((tid >> 3) & 3)) << 4);
    const int r0 = tid >> 2;       // rows 0..63; second issue covers rows 64..127
    const size_t so_i = ((size_t)(i0 + r0) << 10) + xnib;
    const size_t so_j = ((size_t)(j0 + r0) << 10) + xnib;
    const int wbase = wid * 1024;  // wave-uniform LDS dest base

    const char* bx = (const char*)Xn;
    const char* by = (const char*)Yn;

    auto STAGE = [&](int st, int ks) {
        char* base = &lds[st * 32768];
        const size_t ko = (size_t)ks << 6;
        const size_t h = (size_t)64 << 10;   // +64 rows
        GL16(bx + so_j + ko,     base + 0 * 8192 + wbase);          // J_X rows 0..63
        GL16(bx + so_j + h + ko, base + 0 * 8192 + 4096 + wbase);   // J_X rows 64..127
        GL16(by + so_j + ko,     base + 1 * 8192 + wbase);          // J_Y
        GL16(by + so_j + h + ko, base + 1 * 8192 + 4096 + wbase);
        GL16(bx + so_i + ko,     base + 2 * 8192 + wbase);          // I_X
        GL16(bx + so_i + h + ko, base + 2 * 8192 + 4096 + wbase);
        GL16(by + so_i + ko,     base + 3 * 8192 + wbase);          // I_Y
        GL16(by + so_i + h + ko, base + 3 * 8192 + 4096 + wbase);
    };

    // swizzled fragment read offset
    const int rdx = ((lane & 15) << 6) + ((((lane >> 4) ^ ((lane >> 1) & 3))) << 4);
    const int jbase = m * 8192;                        // + fj*1024
    const int ibase = 16384 + m * 8192 + iq * 4096;    // + fi*1024

    f32x4 acc[8][4];   // [fj][fi]
    #pragma unroll
    for (int fj = 0; fj < 8; ++fj)
        #pragma unroll
        for (int fi = 0; fi < 4; ++fi)
            acc[fj][fi] = f32x4{0.f, 0.f, 0.f, 0.f};

    STAGE(0, 0);

    for (int s = 0; s < KSTEPS; ++s) {
        // only stage-s's 8 DMAs are outstanding here (s+1 issued below) -> counted wait
        asm volatile("s_waitcnt vmcnt(0)" ::: "memory");
        __builtin_amdgcn_s_barrier();
        asm volatile("" ::: "memory");

        const char* base = &lds[(s & 1) * 32768];
        bf16x8 aJ[8], bI[4];
        #pragma unroll
        for (int fj = 0; fj < 8; ++fj)
            aJ[fj] = *reinterpret_cast<const bf16x8*>(base + jbase + fj * 1024 + rdx);
        #pragma unroll
        for (int fi = 0; fi < 4; ++fi)
            bI[fi] = *reinterpret_cast<const bf16x8*>(base + ibase + fi * 1024 + rdx);

        if (s + 1 < KSTEPS) STAGE((s + 1) & 1, s + 1);   // prefetch next buffer

        #pragma unroll
        for (int fj = 0; fj < 8; ++fj)
            #pragma unroll
            for (int fi = 0; fi < 4; ++fi)
                acc[fj][fi] = __builtin_amdgcn_mfma_f32_16x16x32_bf16(aJ[fj], bI[fi], acc[fj][fi], 0, 0, 0);
    }

    // ---------------- chunked epilogue (register-lean) ----------------
    // stage buffers dead: chunk scratch [0,8K), jpart [8K,12K)
    char*  chunk = &lds[0];
    float* jpart = reinterpret_cast<float*>(&lds[8192]);  // [iq][128 j][4]

    const int sub = lane >> 4;
    float Si[4] = {0,0,0,0}, Ui[4] = {0,0,0,0}, Vi[4] = {0,0,0,0}, Qi[4] = {0,0,0,0};

    __syncthreads();

    #pragma unroll
    for (int fj = 0; fj < 8; ++fj) {
        if (m == 1) {   // P-waves dump this fj slice (8KB total)
            #pragma unroll
            for (int fi = 0; fi < 4; ++fi)
                *reinterpret_cast<f32x4*>(chunk + iq * 4096 + fi * 1024 + lane * 16) = acc[fj][fi];
        }
        __syncthreads();
        if (m == 0) {   // T-waves pair with matching P slice
            float js[4][4];
            #pragma unroll
            for (int r = 0; r < 4; ++r) { js[r][0]=0; js[r][1]=0; js[r][2]=0; js[r][3]=0; }
            #pragma unroll
            for (int fi = 0; fi < 4; ++fi) {
                const f32x4 pb = *reinterpret_cast<const f32x4*>(chunk + iq * 4096 + fi * 1024 + lane * 16);
                #pragma unroll
                for (int r = 0; r < 4; ++r) {
                    const float a = -acc[fj][fi][r];
                    const float b = -pb[r];
                    const float ea = __expf(a);
                    const float eb = __expf(b);
                    Si[fi] += ea; Ui[fi] += ea * a; Vi[fi] += ea * b; Qi[fi] += eb;
                    js[r][0] += ea; js[r][1] += ea * a; js[r][2] += ea * b; js[r][3] += eb;
                }
            }
            if (p != q) {   // mirror j-sums: reduce over the 16 i-lanes
                #pragma unroll
                for (int r = 0; r < 4; ++r)
                    #pragma unroll
                    for (int c = 0; c < 4; ++c) {
                        #pragma unroll
                        for (int mk = 1; mk <= 8; mk <<= 1)
                            js[r][c] += __shfl_xor(js[r][c], mk);
                    }
                if ((lane & 15) == 0) {
                    #pragma unroll
                    for (int r = 0; r < 4; ++r) {
                        const int j = fj * 16 + sub * 4 + r;
                        #pragma unroll
                        for (int c = 0; c < 4; ++c)
                            jpart[(iq * 128 + j) * 4 + c] = js[r][c];
                    }
                }
            }
        }
        __syncthreads();
    }

    // direct row-i sums: reduce across the 4 j-subgroups, write slot q
    if (m == 0) {
        #pragma unroll
        for (int fi = 0; fi < 4; ++fi) {
            #pragma unroll
            for (int mk = 16; mk <= 32; mk <<= 1) {
                Si[fi] += __shfl_xor(Si[fi], mk);
                Ui[fi] += __shfl_xor(Ui[fi], mk);
                Vi[fi] += __shfl_xor(Vi[fi], mk);
                Qi[fi] += __shfl_xor(Qi[fi], mk);
            }
        }
        if (lane < 16) {
            #pragma unroll
            for (int fi = 0; fi < 4; ++fi) {
                const int row = i0 + iq * 64 + fi * 16 + lane;
                partials[(size_t)row * NSLOT + q] = float4{Si[fi], Ui[fi], Vi[fi], Qi[fi]};
            }
        }
    }
    __syncthreads();

    // mirror combine across iq halves, write slot p (off-diagonal tiles only)
    if (p != q && wid == 0) {
        #pragma unroll
        for (int h = 0; h < 2; ++h) {
            const int j = h * 64 + lane;
            float4 v;
            v.x = jpart[(0 * 128 + j) * 4 + 0] + jpart[(1 * 128 + j) * 4 + 0];
            v.y = jpart[(0 * 128 + j) * 4 + 1] + jpart[(1 * 128 + j) * 4 + 1];
            v.z = jpart[(0 * 128 + j) * 4 + 2] + jpart[(1 * 128 + j) * 4 + 2];
            v.w = jpart[(0 * 128 + j) * 4 + 3] + jpart[(1 * 128 + j) * 4 + 3];
            partials[(size_t)(j0 + j) * NSLOT + p] = v;
        }
    }
}

// ---------------- kernel 3: merge partial sums -> per-row KL, block-reduce ----------------
__global__ __launch_bounds__(256)
void merge_kernel(const float4* __restrict__ partials, float* __restrict__ blocksum)
{
    __shared__ float w[4];
    const int row = blockIdx.x * 256 + threadIdx.x;
    float S = 0.f, U = 0.f, V = 0.f, Q = 0.f;
    #pragma unroll
    for (int s = 0; s < NSLOT; ++s) {
        const float4 pp = partials[(size_t)row * NSLOT + s];
        S += pp.x; U += pp.y; V += pp.z; Q += pp.w;
    }
    float kl = (U - V) / S - logf(S) + logf(Q);
    #pragma unroll
    for (int mm = 1; mm < 64; mm <<= 1) kl += __shfl_xor(kl, mm);
    if ((threadIdx.x & 63) == 0) w[threadIdx.x >> 6] = kl;
    __syncthreads();
    if (threadIdx.x == 0) blocksum[blockIdx.x] = w[0] + w[1] + w[2] + w[3];
}

// ---------------- kernel 4: final mean ----------------
__global__ __launch_bounds__(64)
void reduce_kernel(const float* __restrict__ blocksum, float* __restrict__ out)
{
    float v = (threadIdx.x < 16) ? blocksum[threadIdx.x] : 0.f;
    #pragma unroll
    for (int mm = 1; mm < 16; mm <<= 1) v += __shfl_xor(v, mm);
    if (threadIdx.x == 0) out[0] = v / (float)NROWS;
}

// ---------------- launch ----------------
extern "C" void kernel_launch(void* const* d_in, const int* in_sizes, int n_in,
                              void* d_out, int out_size, void* d_ws, size_t ws_size,
                              hipStream_t stream)
{
    const float* X = (const float*)d_in[0];   // cosine_distance_latent (target)
    const float* Y = (const float*)d_in[1];   // mse_latent (predicted)
    float* out = (float*)d_out;

    char* ws = (char*)d_ws;
    const size_t mat_bytes = (size_t)NROWS * DIM * sizeof(__bf16);          // 4 MiB each
    __bf16* Xn = (__bf16*)ws;
    __bf16* Yn = (__bf16*)(ws + mat_bytes);
    float4* partials = (float4*)(ws + 2 * mat_bytes);                       // 2 MiB
    float* blocksum = (float*)(ws + 2 * mat_bytes + (size_t)NROWS * NSLOT * sizeof(float4));

    normalize_kernel<<<dim3(NROWS / 4, 2), 256, 0, stream>>>(X, Y, Xn, Yn);
    gram_kl_kernel<<<NTILES, 256, 0, stream>>>(Xn, Yn, partials);
    merge_kernel<<<NROWS / 256, 256, 0, stream>>>(partials, blocksum);
    reduce_kernel<<<1, 64, 0, stream>>>(blocksum, out);
}

// Round 12
// 67.931 us; speedup vs baseline: 1.0438x; 1.0438x over previous
//
#include <hip/hip_runtime.h>
#include <math.h>

// ---------------- problem constants ----------------
#define NROWS 4096
#define DIM   512
#define UNIT  128                  // tile edge
#define NP    (NROWS / UNIT)       // 32 row/col blocks
#define NTILES (NP * (NP + 1) / 2) // 528 lower-triangle tiles (= 8 * 66)
#define KSTEPS (DIM / 32)          // 16 K-steps of 32
#define NSLOT NP                   // 32 partial slots per row (direct+mirror, disjoint)

typedef __bf16 bf16x8 __attribute__((ext_vector_type(8)));
typedef float  f32x4  __attribute__((ext_vector_type(4)));

#define GL16(G, L) __builtin_amdgcn_global_load_lds( \
    (const __attribute__((address_space(1))) void*)(G), \
    (__attribute__((address_space(3))) void*)(L), 16, 0, 0)

// ---------------- kernel 1: row-normalize to bf16 (4 rows/block) ----------------
__global__ __launch_bounds__(256)
void normalize_kernel(const float* __restrict__ X, const float* __restrict__ Y,
                      __bf16* __restrict__ Xn, __bf16* __restrict__ Yn)
{
    const int wid  = threadIdx.x >> 6;
    const int lane = threadIdx.x & 63;
    const int row  = blockIdx.x * 4 + wid;
    const float* src = blockIdx.y ? Y : X;
    __bf16*      dst = blockIdx.y ? Yn : Xn;

    const float4* s4 = reinterpret_cast<const float4*>(src + (size_t)row * DIM);
    float4 v0 = s4[lane * 2 + 0];
    float4 v1 = s4[lane * 2 + 1];
    float ss = v0.x*v0.x + v0.y*v0.y + v0.z*v0.z + v0.w*v0.w
             + v1.x*v1.x + v1.y*v1.y + v1.z*v1.z + v1.w*v1.w;
    #pragma unroll
    for (int m = 1; m < 64; m <<= 1) ss += __shfl_xor(ss, m);
    const float scale = 1.0f / fmaxf(sqrtf(ss), 1e-8f);

    bf16x8 o;
    o[0] = (__bf16)(v0.x * scale); o[1] = (__bf16)(v0.y * scale);
    o[2] = (__bf16)(v0.z * scale); o[3] = (__bf16)(v0.w * scale);
    o[4] = (__bf16)(v1.x * scale); o[5] = (__bf16)(v1.y * scale);
    o[6] = (__bf16)(v1.z * scale); o[7] = (__bf16)(v1.w * scale);
    *reinterpret_cast<bf16x8*>(dst + (size_t)row * DIM + lane * 8) = o;
}

// ---------------- kernel 2: symmetric-triangle gram + exp-sum partials ----------------
// Tile (p, q), q <= p, 128x128, both matrices. 4 waves: m = wid>>1 (matrix),
// iq = wid&1 (i-half). Wave: C[j,i] = sum_k J[j,k]*I[i,k] over 128j x 64i
// (swapped operands: j lane-local; i = iq*64 + fi*16 + (lane&15)).
// Direct row-i sums -> slot q; mirror row-j sums -> slot p (p != q only).
// PIPELINE (the R11->R12 change): J panels 3-stage (depth-2 prefetch), I panels
// 2-stage (depth-1). Per-wave vmcnt FIFO at step top = [J_s, I_s, J_{s+1}] ->
// s_waitcnt vmcnt(4) drains {J_s, I_s}, keeps J_{s+1} in flight ACROSS the
// barrier (counted vmcnt, never 0 mid-loop - T4). LDS 80KB -> 2 blocks/CU.
__global__ __launch_bounds__(256, 2)
void gram_kl_kernel(const __bf16* __restrict__ Xn, const __bf16* __restrict__ Yn,
                    float4* __restrict__ partials)
{
    // [0,48K): J stages x3 (16KB: JX 8K | JY 8K); [48K,80K): I stages x2 (16KB each)
    __shared__ char lds[81920];

    const int tid  = threadIdx.x;
    const int wid  = tid >> 6;     // 0..3
    const int lane = tid & 63;
    const int m  = wid >> 1;       // matrix select (0=X/target, 1=Y/pred)
    const int iq = wid & 1;        // i-half

    // XCD-chunked map over 528 = 8 * 66, then triangular decode (q <= p)
    const int glin = (blockIdx.x & 7) * (NTILES / 8) + (blockIdx.x >> 3);
    int p = (int)((sqrtf((float)(8 * glin + 1)) - 1.0f) * 0.5f);
    while ((p + 1) * (p + 2) / 2 <= glin) ++p;
    while (p * (p + 1) / 2 > glin) --p;
    const int q = glin - p * (p + 1) / 2;
    const int i0 = p * UNIT;
    const int j0 = q * UNIT;

    // ---- staging source offsets (pre-swizzled global, linear LDS dest) ----
    // 16B unit u of a 64-row half-panel: row = u>>2, LDS slot u&3 holds global
    // seg (u&3)^((row>>1)&3)
    const int xnib = (((tid & 3) ^ ((tid >> 3) & 3)) << 4);
    const int r0 = tid >> 2;       // rows 0..63; +h covers rows 64..127
    const size_t so_i = ((size_t)(i0 + r0) << 10) + xnib;
    const size_t so_j = ((size_t)(j0 + r0) << 10) + xnib;
    const int wbase = wid * 1024;  // wave-uniform LDS dest base

    const char* bx = (const char*)Xn;
    const char* by = (const char*)Yn;

    auto STAGE_J = [&](int st, int ks) {
        char* base = &lds[st * 16384];
        const size_t ko = (size_t)ks << 6;
        const size_t h = (size_t)64 << 10;
        GL16(bx + so_j + ko,     base + 0    + wbase);   // J_X rows 0..63
        GL16(bx + so_j + h + ko, base + 4096 + wbase);   // J_X rows 64..127
        GL16(by + so_j + ko,     base + 8192 + wbase);   // J_Y rows 0..63
        GL16(by + so_j + h + ko, base + 12288 + wbase);  // J_Y rows 64..127
    };
    auto STAGE_I = [&](int ib, int ks) {
        char* base = &lds[49152 + ib * 16384];
        const size_t ko = (size_t)ks << 6;
        const size_t h = (size_t)64 << 10;
        GL16(bx + so_i + ko,     base + 0    + wbase);   // I_X rows 0..63
        GL16(bx + so_i + h + ko, base + 4096 + wbase);   // I_X rows 64..127
        GL16(by + so_i + ko,     base + 8192 + wbase);   // I_Y rows 0..63
        GL16(by + so_i + h + ko, base + 12288 + wbase);  // I_Y rows 64..127
    };

    // swizzled fragment read offset: row-part + xor'd 16B segment
    const int rdx = ((lane & 15) << 6) + ((((lane >> 4) ^ ((lane >> 1) & 3))) << 4);

    f32x4 acc[8][4];   // [fj][fi]
    #pragma unroll
    for (int fj = 0; fj < 8; ++fj)
        #pragma unroll
        for (int fi = 0; fi < 4; ++fi)
            acc[fj][fi] = f32x4{0.f, 0.f, 0.f, 0.f};

    // prologue: per-wave vmcnt FIFO = [I0(4), J0(4), J1(4)]
    STAGE_I(0, 0);
    STAGE_J(0, 0);
    STAGE_J(1, 1);

    for (int s = 0; s < KSTEPS; ++s) {
        // steady-state FIFO at top: [J_s(4), I_s(4), J_{s+1}(4)]
        // vmcnt(4): drain J_s + I_s, keep J_{s+1} in flight across the barrier
        if (s < KSTEPS - 1) asm volatile("s_waitcnt vmcnt(4)" ::: "memory");
        else                asm volatile("s_waitcnt vmcnt(0)" ::: "memory");
        __builtin_amdgcn_s_barrier();
        asm volatile("" ::: "memory");

        const char* jb = &lds[(s % 3) * 16384 + m * 8192];
        const char* ib = &lds[49152 + (s & 1) * 16384 + m * 8192 + iq * 4096];

        bf16x8 aJ[8], bI[4];
        #pragma unroll
        for (int fj = 0; fj < 8; ++fj)
            aJ[fj] = *reinterpret_cast<const bf16x8*>(jb + fj * 1024 + rdx);
        #pragma unroll
        for (int fi = 0; fi < 4; ++fi)
            bI[fi] = *reinterpret_cast<const bf16x8*>(ib + fi * 1024 + rdx);

        // issue order matters for the FIFO: I_{s+1} first, then J_{s+2}
        if (s + 1 < KSTEPS) STAGE_I((s + 1) & 1, s + 1);
        if (s + 2 < KSTEPS) STAGE_J((s + 2) % 3, s + 2);

        #pragma unroll
        for (int fj = 0; fj < 8; ++fj)
            #pragma unroll
            for (int fi = 0; fi < 4; ++fi)
                acc[fj][fi] = __builtin_amdgcn_mfma_f32_16x16x32_bf16(aJ[fj], bI[fi], acc[fj][fi], 0, 0, 0);
    }

    // ---------------- chunked epilogue (register-lean, verified in R11) ----------------
    // stage buffers dead: chunk scratch [0,8K), jpart [8K,12K)
    char*  chunk = &lds[0];
    float* jpart = reinterpret_cast<float*>(&lds[8192]);  // [iq][128 j][4]

    const int sub = lane >> 4;
    float Si[4] = {0,0,0,0}, Ui[4] = {0,0,0,0}, Vi[4] = {0,0,0,0}, Qi[4] = {0,0,0,0};

    __syncthreads();

    #pragma unroll
    for (int fj = 0; fj < 8; ++fj) {
        if (m == 1) {   // P-waves dump this fj slice (8KB total)
            #pragma unroll
            for (int fi = 0; fi < 4; ++fi)
                *reinterpret_cast<f32x4*>(chunk + iq * 4096 + fi * 1024 + lane * 16) = acc[fj][fi];
        }
        __syncthreads();
        if (m == 0) {   // T-waves pair with matching P slice
            float js[4][4];
            #pragma unroll
            for (int r = 0; r < 4; ++r) { js[r][0]=0; js[r][1]=0; js[r][2]=0; js[r][3]=0; }
            #pragma unroll
            for (int fi = 0; fi < 4; ++fi) {
                const f32x4 pb = *reinterpret_cast<const f32x4*>(chunk + iq * 4096 + fi * 1024 + lane * 16);
                #pragma unroll
                for (int r = 0; r < 4; ++r) {
                    const float a = -acc[fj][fi][r];
                    const float b = -pb[r];
                    const float ea = __expf(a);
                    const float eb = __expf(b);
                    Si[fi] += ea; Ui[fi] += ea * a; Vi[fi] += ea * b; Qi[fi] += eb;
                    js[r][0] += ea; js[r][1] += ea * a; js[r][2] += ea * b; js[r][3] += eb;
                }
            }
            if (p != q) {   // mirror j-sums: reduce over the 16 i-lanes
                #pragma unroll
                for (int r = 0; r < 4; ++r)
                    #pragma unroll
                    for (int c = 0; c < 4; ++c) {
                        #pragma unroll
                        for (int mk = 1; mk <= 8; mk <<= 1)
                            js[r][c] += __shfl_xor(js[r][c], mk);
                    }
                if ((lane & 15) == 0) {
                    #pragma unroll
                    for (int r = 0; r < 4; ++r) {
                        const int j = fj * 16 + sub * 4 + r;
                        #pragma unroll
                        for (int c = 0; c < 4; ++c)
                            jpart[(iq * 128 + j) * 4 + c] = js[r][c];
                    }
                }
            }
        }
        __syncthreads();
    }

    // direct row-i sums: reduce across the 4 j-subgroups, write slot q
    if (m == 0) {
        #pragma unroll
        for (int fi = 0; fi < 4; ++fi) {
            #pragma unroll
            for (int mk = 16; mk <= 32; mk <<= 1) {
                Si[fi] += __shfl_xor(Si[fi], mk);
                Ui[fi] += __shfl_xor(Ui[fi], mk);
                Vi[fi] += __shfl_xor(Vi[fi], mk);
                Qi[fi] += __shfl_xor(Qi[fi], mk);
            }
        }
        if (lane < 16) {
            #pragma unroll
            for (int fi = 0; fi < 4; ++fi) {
                const int row = i0 + iq * 64 + fi * 16 + lane;
                partials[(size_t)row * NSLOT + q] = float4{Si[fi], Ui[fi], Vi[fi], Qi[fi]};
            }
        }
    }
    __syncthreads();

    // mirror combine across iq halves, write slot p (off-diagonal tiles only)
    if (p != q && wid == 0) {
        #pragma unroll
        for (int h = 0; h < 2; ++h) {
            const int j = h * 64 + lane;
            float4 v;
            v.x = jpart[(0 * 128 + j) * 4 + 0] + jpart[(1 * 128 + j) * 4 + 0];
            v.y = jpart[(0 * 128 + j) * 4 + 1] + jpart[(1 * 128 + j) * 4 + 1];
            v.z = jpart[(0 * 128 + j) * 4 + 2] + jpart[(1 * 128 + j) * 4 + 2];
            v.w = jpart[(0 * 128 + j) * 4 + 3] + jpart[(1 * 128 + j) * 4 + 3];
            partials[(size_t)(j0 + j) * NSLOT + p] = v;
        }
    }
}

// ---------------- kernel 3: merge partial sums -> per-row KL, block-reduce ----------------
__global__ __launch_bounds__(256)
void merge_kernel(const float4* __restrict__ partials, float* __restrict__ blocksum)
{
    __shared__ float w[4];
    const int row = blockIdx.x * 256 + threadIdx.x;
    float S = 0.f, U = 0.f, V = 0.f, Q = 0.f;
    #pragma unroll
    for (int s = 0; s < NSLOT; ++s) {
        const float4 pp = partials[(size_t)row * NSLOT + s];
        S += pp.x; U += pp.y; V += pp.z; Q += pp.w;
    }
    float kl = (U - V) / S - logf(S) + logf(Q);
    #pragma unroll
    for (int mm = 1; mm < 64; mm <<= 1) kl += __shfl_xor(kl, mm);
    if ((threadIdx.x & 63) == 0) w[threadIdx.x >> 6] = kl;
    __syncthreads();
    if (threadIdx.x == 0) blocksum[blockIdx.x] = w[0] + w[1] + w[2] + w[3];
}

// ---------------- kernel 4: final mean ----------------
__global__ __launch_bounds__(64)
void reduce_kernel(const float* __restrict__ blocksum, float* __restrict__ out)
{
    float v = (threadIdx.x < 16) ? blocksum[threadIdx.x] : 0.f;
    #pragma unroll
    for (int mm = 1; mm < 16; mm <<= 1) v += __shfl_xor(v, mm);
    if (threadIdx.x == 0) out[0] = v / (float)NROWS;
}

// ---------------- launch ----------------
extern "C" void kernel_launch(void* const* d_in, const int* in_sizes, int n_in,
                              void* d_out, int out_size, void* d_ws, size_t ws_size,
                              hipStream_t stream)
{
    const float* X = (const float*)d_in[0];   // cosine_distance_latent (target)
    const float* Y = (const float*)d_in[1];   // mse_latent (predicted)
    float* out = (float*)d_out;

    char* ws = (char*)d_ws;
    const size_t mat_bytes = (size_t)NROWS * DIM * sizeof(__bf16);          // 4 MiB each
    __bf16* Xn = (__bf16*)ws;
    __bf16* Yn = (__bf16*)(ws + mat_bytes);
    float4* partials = (float4*)(ws + 2 * mat_bytes);                       // 2 MiB
    float* blocksum = (float*)(ws + 2 * mat_bytes + (size_t)NROWS * NSLOT * sizeof(float4));

    normalize_kernel<<<dim3(NROWS / 4, 2), 256, 0, stream>>>(X, Y, Xn, Yn);
    gram_kl_kernel<<<NTILES, 256, 0, stream>>>(Xn, Yn, partials);
    merge_kernel<<<NROWS / 256, 256, 0, stream>>>(partials, blocksum);
    reduce_kernel<<<1, 64, 0, stream>>>(blocksum, out);
}

// Round 13
// 67.436 us; speedup vs baseline: 1.0514x; 1.0073x over previous
//
#include <hip/hip_runtime.h>
#include <math.h>

// ---------------- problem constants ----------------
#define NROWS 4096
#define DIM   512
#define UNIT_I 128                 // grain i-rows
#define UNIT_J 64                  // grain j-rows
#define NPI   (NROWS / UNIT_I)     // 32 i-blocks
#define NGRAINS 1056               // sum_{p<32}(2p+2) = 8 * 132
#define KSTEPS (DIM / 32)          // 16 K-steps of 32
#define NSLOT 64                   // partial slots per row (direct+mirror, gap-free)

typedef __bf16 bf16x8 __attribute__((ext_vector_type(8)));
typedef float  f32x4  __attribute__((ext_vector_type(4)));

#define GL16(G, L) __builtin_amdgcn_global_load_lds( \
    (const __attribute__((address_space(1))) void*)(G), \
    (__attribute__((address_space(3))) void*)(L), 16, 0, 0)

// ---------------- kernel 1: row-normalize to bf16 (4 rows/block) ----------------
__global__ __launch_bounds__(256)
void normalize_kernel(const float* __restrict__ X, const float* __restrict__ Y,
                      __bf16* __restrict__ Xn, __bf16* __restrict__ Yn)
{
    const int wid  = threadIdx.x >> 6;
    const int lane = threadIdx.x & 63;
    const int row  = blockIdx.x * 4 + wid;
    const float* src = blockIdx.y ? Y : X;
    __bf16*      dst = blockIdx.y ? Yn : Xn;

    const float4* s4 = reinterpret_cast<const float4*>(src + (size_t)row * DIM);
    float4 v0 = s4[lane * 2 + 0];
    float4 v1 = s4[lane * 2 + 1];
    float ss = v0.x*v0.x + v0.y*v0.y + v0.z*v0.z + v0.w*v0.w
             + v1.x*v1.x + v1.y*v1.y + v1.z*v1.z + v1.w*v1.w;
    #pragma unroll
    for (int m = 1; m < 64; m <<= 1) ss += __shfl_xor(ss, m);
    const float scale = 1.0f / fmaxf(sqrtf(ss), 1e-8f);

    bf16x8 o;
    o[0] = (__bf16)(v0.x * scale); o[1] = (__bf16)(v0.y * scale);
    o[2] = (__bf16)(v0.z * scale); o[3] = (__bf16)(v0.w * scale);
    o[4] = (__bf16)(v1.x * scale); o[5] = (__bf16)(v1.y * scale);
    o[6] = (__bf16)(v1.z * scale); o[7] = (__bf16)(v1.w * scale);
    *reinterpret_cast<bf16x8*>(dst + (size_t)row * DIM + lane * 8) = o;
}

// ---------------- kernel 2: symmetric-triangle gram + exp-sum partials ----------------
// GRAIN (p, q): i-rows [128p, 128p+128), j-rows [64q, 64q+64), q in [0, 2p+2).
// 1056 grains (= 8*132): fine grains + 3 blocks/CU residency kill the R11/R12
// scheduling tail (528 @ 2/CU left 16 stragglers = 2x makespan).
// 4 waves: m = wid>>1 (0=X/target, 1=Y/pred); iq = wid&1 (i-half of 64).
// Wave: C[j,i] = sum_k J[j,k]*I[i,k] over 64j x 64i (swapped operands:
// j = fj*16 + (lane>>4)*4 + r lane-local; i = iq*64 + fi*16 + (lane&15)).
// Direct row-i sums -> slot q; mirror row-j sums -> slot (q>>1)+p+1 (skip when
// p == q>>1: those j-rows lie inside the i-block and are covered directly).
// Per row r: direct slots [0, 2*(r>>7)+2), mirror slots [.., (r>>7)+33) - gap-free.
// Logits a=-simT, b=-simP in [-1,1] -> plain sums S,U,V,Q (no max tracking).
__global__ __launch_bounds__(256, 3)
void gram_kl_kernel(const __bf16* __restrict__ Xn, const __bf16* __restrict__ Yn,
                    float4* __restrict__ partials)
{
    // 2 stages x 24KB: [J_X 4K | J_Y 4K | I_X 8K | I_Y 8K]; epilogue aliases stage 0
    __shared__ char lds[49152];

    const int tid  = threadIdx.x;
    const int wid  = tid >> 6;     // 0..3
    const int lane = tid & 63;
    const int m  = wid >> 1;       // matrix select (0=X/target, 1=Y/pred)
    const int iq = wid & 1;        // i-half

    // XCD-chunked map over 1056 = 8 * 132, then triangular decode
    // cum(p) = p^2 + p grains before i-block p
    const int gl = (blockIdx.x & 7) * (NGRAINS / 8) + (blockIdx.x >> 3);
    int p = (int)((sqrtf((float)(4 * gl + 1)) - 1.0f) * 0.5f);
    while ((p + 1) * (p + 2) <= gl) ++p;   // cum(p+1) = (p+1)^2+(p+1) = (p+1)(p+2)
    while (p * (p + 1) > gl) --p;
    const int q = gl - p * (p + 1);        // q in [0, 2p+2)
    const int i0 = p * UNIT_I;
    const int j0 = q * UNIT_J;
    const int diag = (p == (q >> 1));      // j-rows inside i-block -> no mirror

    // ---- staging source offsets (pre-swizzled global, linear LDS dest) ----
    // 16B unit u of a 64-row half-panel: row = u>>2, LDS slot u&3 holds global
    // seg (u&3)^((row>>1)&3)
    const int xnib = (((tid & 3) ^ ((tid >> 3) & 3)) << 4);
    const int r0 = tid >> 2;       // rows 0..63
    const size_t so_i = ((size_t)(i0 + r0) << 10) + xnib;
    const size_t so_j = ((size_t)(j0 + r0) << 10) + xnib;
    const int wbase = wid * 1024;  // wave-uniform LDS dest base

    const char* bx = (const char*)Xn;
    const char* by = (const char*)Yn;

    auto STAGE = [&](int st, int ks) {
        char* base = &lds[st * 24576];
        const size_t ko = (size_t)ks << 6;
        const size_t h = (size_t)64 << 10;   // +64 rows (I panel second half)
        GL16(bx + so_j + ko,     base + 0     + wbase);   // J_X (64 rows)
        GL16(by + so_j + ko,     base + 4096  + wbase);   // J_Y
        GL16(bx + so_i + ko,     base + 8192  + wbase);   // I_X rows 0..63
        GL16(bx + so_i + h + ko, base + 12288 + wbase);   // I_X rows 64..127
        GL16(by + so_i + ko,     base + 16384 + wbase);   // I_Y rows 0..63
        GL16(by + so_i + h + ko, base + 20480 + wbase);   // I_Y rows 64..127
    };

    // swizzled fragment read offset: row-part + xor'd 16B segment
    const int rdx = ((lane & 15) << 6) + ((((lane >> 4) ^ ((lane >> 1) & 3))) << 4);

    f32x4 acc[4][4];   // [fj][fi]
    #pragma unroll
    for (int fj = 0; fj < 4; ++fj)
        #pragma unroll
        for (int fi = 0; fi < 4; ++fi)
            acc[fj][fi] = f32x4{0.f, 0.f, 0.f, 0.f};

    STAGE(0, 0);

    for (int s = 0; s < KSTEPS; ++s) {
        asm volatile("s_waitcnt vmcnt(0)" ::: "memory");   // stage s complete
        __builtin_amdgcn_s_barrier();
        asm volatile("" ::: "memory");

        const char* base = &lds[(s & 1) * 24576];
        const char* jb = base + m * 4096;
        const char* ib = base + 8192 + m * 8192 + iq * 4096;

        bf16x8 aJ[4], bI[4];
        #pragma unroll
        for (int fj = 0; fj < 4; ++fj)
            aJ[fj] = *reinterpret_cast<const bf16x8*>(jb + fj * 1024 + rdx);
        #pragma unroll
        for (int fi = 0; fi < 4; ++fi)
            bI[fi] = *reinterpret_cast<const bf16x8*>(ib + fi * 1024 + rdx);

        if (s + 1 < KSTEPS) STAGE((s + 1) & 1, s + 1);     // prefetch next buffer

        #pragma unroll
        for (int fj = 0; fj < 4; ++fj)
            #pragma unroll
            for (int fi = 0; fi < 4; ++fi)
                acc[fj][fi] = __builtin_amdgcn_mfma_f32_16x16x32_bf16(aJ[fj], bI[fi], acc[fj][fi], 0, 0, 0);
    }

    // ---------------- chunked epilogue (register-lean, R11-verified pattern) ----------------
    // stage buffers dead: chunk scratch [0,8K), jpart [8K,10K)
    char*  chunk = &lds[0];
    float* jpart = reinterpret_cast<float*>(&lds[8192]);  // [iq][64 j][4]

    const int sub = lane >> 4;
    float Si[4] = {0,0,0,0}, Ui[4] = {0,0,0,0}, Vi[4] = {0,0,0,0}, Qi[4] = {0,0,0,0};

    __syncthreads();

    #pragma unroll
    for (int fj = 0; fj < 4; ++fj) {
        if (m == 1) {   // P-waves dump this fj slice (8KB total)
            #pragma unroll
            for (int fi = 0; fi < 4; ++fi)
                *reinterpret_cast<f32x4*>(chunk + iq * 4096 + fi * 1024 + lane * 16) = acc[fj][fi];
        }
        __syncthreads();
        if (m == 0) {   // T-waves pair with matching P slice
            float js[4][4];
            #pragma unroll
            for (int r = 0; r < 4; ++r) { js[r][0]=0; js[r][1]=0; js[r][2]=0; js[r][3]=0; }
            #pragma unroll
            for (int fi = 0; fi < 4; ++fi) {
                const f32x4 pb = *reinterpret_cast<const f32x4*>(chunk + iq * 4096 + fi * 1024 + lane * 16);
                #pragma unroll
                for (int r = 0; r < 4; ++r) {
                    const float a = -acc[fj][fi][r];
                    const float b = -pb[r];
                    const float ea = __expf(a);
                    const float eb = __expf(b);
                    Si[fi] += ea; Ui[fi] += ea * a; Vi[fi] += ea * b; Qi[fi] += eb;
                    js[r][0] += ea; js[r][1] += ea * a; js[r][2] += ea * b; js[r][3] += eb;
                }
            }
            if (!diag) {   // mirror j-sums: reduce over the 16 i-lanes
                #pragma unroll
                for (int r = 0; r < 4; ++r)
                    #pragma unroll
                    for (int c = 0; c < 4; ++c) {
                        #pragma unroll
                        for (int mk = 1; mk <= 8; mk <<= 1)
                            js[r][c] += __shfl_xor(js[r][c], mk);
                    }
                if ((lane & 15) == 0) {
                    #pragma unroll
                    for (int r = 0; r < 4; ++r) {
                        const int j = fj * 16 + sub * 4 + r;
                        #pragma unroll
                        for (int c = 0; c < 4; ++c)
                            jpart[(iq * 64 + j) * 4 + c] = js[r][c];
                    }
                }
            }
        }
        __syncthreads();
    }

    // direct row-i sums: reduce across the 4 j-subgroups, write slot q
    if (m == 0) {
        #pragma unroll
        for (int fi = 0; fi < 4; ++fi) {
            #pragma unroll
            for (int mk = 16; mk <= 32; mk <<= 1) {
                Si[fi] += __shfl_xor(Si[fi], mk);
                Ui[fi] += __shfl_xor(Ui[fi], mk);
                Vi[fi] += __shfl_xor(Vi[fi], mk);
                Qi[fi] += __shfl_xor(Qi[fi], mk);
            }
        }
        if (lane < 16) {
            #pragma unroll
            for (int fi = 0; fi < 4; ++fi) {
                const int row = i0 + iq * 64 + fi * 16 + lane;
                partials[(size_t)row * NSLOT + q] = float4{Si[fi], Ui[fi], Vi[fi], Qi[fi]};
            }
        }
    }
    __syncthreads();

    // mirror combine across iq halves, write slot (q>>1)+p+1 (off-diagonal only)
    if (!diag && wid == 0) {
        const int j = lane;   // 0..63
        const int mslot = (q >> 1) + p + 1;
        float4 v;
        v.x = jpart[(0 * 64 + j) * 4 + 0] + jpart[(1 * 64 + j) * 4 + 0];
        v.y = jpart[(0 * 64 + j) * 4 + 1] + jpart[(1 * 64 + j) * 4 + 1];
        v.z = jpart[(0 * 64 + j) * 4 + 2] + jpart[(1 * 64 + j) * 4 + 2];
        v.w = jpart[(0 * 64 + j) * 4 + 3] + jpart[(1 * 64 + j) * 4 + 3];
        partials[(size_t)(j0 + j) * NSLOT + mslot] = v;
    }
}

// ---------------- kernel 3: merge partial sums -> per-row KL, block-reduce ----------------
// Row r uses slots [0, (r>>7)+33): direct [0, 2*(r>>7)+2) + mirror [.., (r>>7)+33).
__global__ __launch_bounds__(256)
void merge_kernel(const float4* __restrict__ partials, float* __restrict__ blocksum)
{
    __shared__ float w[4];
    const int row = blockIdx.x * 256 + threadIdx.x;
    const int nsl = (row >> 7) + 33;
    float S = 0.f, U = 0.f, V = 0.f, Q = 0.f;
    for (int s = 0; s < nsl; ++s) {
        const float4 pp = partials[(size_t)row * NSLOT + s];
        S += pp.x; U += pp.y; V += pp.z; Q += pp.w;
    }
    float kl = (U - V) / S - logf(S) + logf(Q);
    #pragma unroll
    for (int mm = 1; mm < 64; mm <<= 1) kl += __shfl_xor(kl, mm);
    if ((threadIdx.x & 63) == 0) w[threadIdx.x >> 6] = kl;
    __syncthreads();
    if (threadIdx.x == 0) blocksum[blockIdx.x] = w[0] + w[1] + w[2] + w[3];
}

// ---------------- kernel 4: final mean ----------------
__global__ __launch_bounds__(64)
void reduce_kernel(const float* __restrict__ blocksum, float* __restrict__ out)
{
    float v = (threadIdx.x < 16) ? blocksum[threadIdx.x] : 0.f;
    #pragma unroll
    for (int mm = 1; mm < 16; mm <<= 1) v += __shfl_xor(v, mm);
    if (threadIdx.x == 0) out[0] = v / (float)NROWS;
}

// ---------------- launch ----------------
extern "C" void kernel_launch(void* const* d_in, const int* in_sizes, int n_in,
                              void* d_out, int out_size, void* d_ws, size_t ws_size,
                              hipStream_t stream)
{
    const float* X = (const float*)d_in[0];   // cosine_distance_latent (target)
    const float* Y = (const float*)d_in[1];   // mse_latent (predicted)
    float* out = (float*)d_out;

    char* ws = (char*)d_ws;
    const size_t mat_bytes = (size_t)NROWS * DIM * sizeof(__bf16);          // 4 MiB each
    __bf16* Xn = (__bf16*)ws;
    __bf16* Yn = (__bf16*)(ws + mat_bytes);
    float4* partials = (float4*)(ws + 2 * mat_bytes);                       // 4096*64*16 B = 4 MiB
    float* blocksum = (float*)(ws + 2 * mat_bytes + (size_t)NROWS * NSLOT * sizeof(float4));

    normalize_kernel<<<dim3(NROWS / 4, 2), 256, 0, stream>>>(X, Y, Xn, Yn);
    gram_kl_kernel<<<NGRAINS, 256, 0, stream>>>(Xn, Yn, partials);
    merge_kernel<<<NROWS / 256, 256, 0, stream>>>(partials, blocksum);
    reduce_kernel<<<1, 64, 0, stream>>>(blocksum, out);
}